// Round 1
// baseline (12572.222 us; speedup 1.0000x reference)
//
#include <hip/hip_runtime.h>
#include <hip/hip_bf16.h>

#define NNODE 16384
#define EDGES 262144
#define KSP 25
#define HOUT 64
#define TSTEPS 10

// ---------------- prep kernels ----------------

// x: (N, FIN=32, T=10) -> xT: (T, N, 32)
__global__ __launch_bounds__(256) void xpose_kernel(const float* __restrict__ x,
                                                    float* __restrict__ xT) {
  const int i = blockIdx.x * 256 + threadIdx.x;   // i = n*32 + f
  if (i >= NNODE * 32) return;
  const float* src = x + (size_t)i * TSTEPS;
  #pragma unroll
  for (int t = 0; t < TSTEPS; ++t)
    xT[(size_t)t * NNODE * 32 + i] = src[t];
}

__global__ __launch_bounds__(256) void deg_kernel(const int* __restrict__ ei,
                                                  int* __restrict__ degi) {
  const int e = blockIdx.x * 256 + threadIdx.x;
  if (e >= EDGES) return;
  atomicAdd(&degi[ei[EDGES + e]], 1);
}

// single-block exclusive scan of 16384 degrees -> row_ptr, plus deg_inv
__global__ __launch_bounds__(1024) void scan_kernel(const int* __restrict__ degi,
                                                    int* __restrict__ rp,
                                                    float* __restrict__ deg_inv) {
  __shared__ int sh[1024];
  const int tid = threadIdx.x;
  const int base = tid * 16;
  int loc[16];
  int sum = 0;
  #pragma unroll
  for (int i = 0; i < 16; ++i) { loc[i] = degi[base + i]; sum += loc[i]; }
  sh[tid] = sum;
  __syncthreads();
  for (int off = 1; off < 1024; off <<= 1) {
    int v = 0;
    if (tid >= off) v = sh[tid - off];
    __syncthreads();
    if (tid >= off) sh[tid] += v;
    __syncthreads();
  }
  int ex = sh[tid] - sum;   // exclusive prefix for this chunk
  #pragma unroll
  for (int i = 0; i < 16; ++i) {
    rp[base + i] = ex;
    ex += loc[i];
    deg_inv[base + i] = 1.f / (float)max(loc[i], 1);
  }
  if (tid == 1023) rp[NNODE] = ex;
}

// scatter edges into CSR (sorted by dst); compute spline basis + widx inline
__global__ __launch_bounds__(256) void scatter_kernel(const int* __restrict__ ei,
                                                      const float* __restrict__ ea,
                                                      const int* __restrict__ rp,
                                                      int* __restrict__ cursor,
                                                      int* __restrict__ esrc,
                                                      unsigned* __restrict__ ewidx,
                                                      float4* __restrict__ ebasis) {
  const int e = blockIdx.x * 256 + threadIdx.x;
  if (e >= EDGES) return;
  const int s = ei[e];
  const int d = ei[EDGES + e];
  const int pos = rp[d] + atomicAdd(&cursor[d], 1);
  const float a0 = ea[2 * e], a1 = ea[2 * e + 1];
  const float f0 = a0 * 4.f, f1 = a1 * 4.f;
  float k0f = fminf(fmaxf(floorf(f0), 0.f), 3.f);
  float k1f = fminf(fmaxf(floorf(f1), 0.f), 3.f);
  const float t0 = f0 - k0f, t1 = f1 - k1f;
  const int k0 = (int)k0f, k1 = (int)k1f;
  // bits order: (0,0),(0,1),(1,0),(1,1); strides (1,5)
  const unsigned w00 = (unsigned)(k0 + 5 * k1);
  const unsigned w01 = (unsigned)(k0 + 5 * (k1 + 1));
  const unsigned w10 = (unsigned)(k0 + 1 + 5 * k1);
  const unsigned w11 = (unsigned)(k0 + 1 + 5 * (k1 + 1));
  esrc[pos] = s;
  ewidx[pos] = w00 | (w01 << 8) | (w10 << 16) | (w11 << 24);
  float4 b;
  b.x = (1.f - t0) * (1.f - t1);
  b.y = (1.f - t0) * t1;
  b.z = t0 * (1.f - t1);
  b.w = t0 * t1;
  ebasis[pos] = b;
}

// ---------------- fused spline-conv kernel (U-form) ----------------

struct ConvP {
  const float* W[5];     // 0:hr 1:hz 2:xr 3:xz 4:xn
  const float* root[5];
  const float* bias[5];
  const float* h;
  const float* xT;
  const int* rp;
  const int* esrc;
  const unsigned* ewidx;
  const float4* ebasis;
  const float* deg_inv;
  float* outs[5];        // 0:hr_buf 1:hz_buf 2:xcr 3:xcz 4:xcn
};

template <int FIN, int NB>
__device__ void conv_body(const float* __restrict__ vin, const float* __restrict__ W,
                          const float* __restrict__ root, const float* __restrict__ bias,
                          const int* __restrict__ rp, const int* __restrict__ esrc,
                          const unsigned* __restrict__ ewidx,
                          const float4* __restrict__ ebasis,
                          const float* __restrict__ deg_inv, float* __restrict__ outp,
                          float* Ush, float* vstage) {
  constexpr int UST = FIN * KSP + 8;   // +8 words: dloc groups land in distinct banks
  constexpr int VO = NB / 4;           // outputs per thread (NB*64/256)
  constexpr int LQ = 256 / NB;         // threads per node in phase 3
  const int tid = threadIdx.x;
  const int d0 = blockIdx.x * NB;
  if (d0 >= NNODE) return;

  // zero U, stage v block (rows of vin are contiguous)
  for (int i = tid; i < NB * UST; i += 256) Ush[i] = 0.f;
  for (int i = tid; i < NB * FIN; i += 256) vstage[i] = vin[(size_t)d0 * FIN + i];
  __syncthreads();

  // phase 2: build U. wave w owns NB/4 dst nodes -> race-free LDS accumulate
  const int wave = tid >> 6, lane = tid & 63;
  constexpr int DPW = NB / 4;
  for (int dd = 0; dd < DPW; ++dd) {
    const int dloc = wave * DPW + dd;
    const int d = d0 + dloc;
    const int e0 = rp[d], e1 = rp[d + 1];
    float* Ub = Ush + dloc * UST;
    if (lane < FIN) {
      for (int e = e0; e < e1; ++e) {
        const float hv = vin[(size_t)esrc[e] * FIN + lane];
        const float4 bs = ebasis[e];
        const unsigned wx = ewidx[e];
        Ub[(wx & 0xffu) * FIN + lane] += bs.x * hv;
        Ub[((wx >> 8) & 0xffu) * FIN + lane] += bs.y * hv;
        Ub[((wx >> 16) & 0xffu) * FIN + lane] += bs.z * hv;
        Ub[(wx >> 24) * FIN + lane] += bs.w * hv;
      }
    }
  }
  __syncthreads();

  // phase 3: agg[d,o] = deg_inv * sum_kf U[d,kf]*W[kf,o] + sum_f v[d,f]*root[f,o] + b[o]
  const int dloc = tid / LQ;
  const int o0 = (tid % LQ) * VO;
  const float* Ub = Ush + dloc * UST;
  float acc[VO];
  #pragma unroll
  for (int j = 0; j < VO; ++j) acc[j] = 0.f;

  for (int kf = 0; kf < KSP * FIN; kf += 4) {
    const float4 u4 = *reinterpret_cast<const float4*>(Ub + kf);
    #pragma unroll
    for (int uu = 0; uu < 4; ++uu) {
      const float u = (uu == 0) ? u4.x : (uu == 1) ? u4.y : (uu == 2) ? u4.z : u4.w;
      const float* wrow = W + (size_t)(kf + uu) * HOUT + o0;
      if constexpr (VO == 2) {
        const float2 w2 = *reinterpret_cast<const float2*>(wrow);
        acc[0] += u * w2.x;
        acc[1] += u * w2.y;
      } else {
        const float4 w4 = *reinterpret_cast<const float4*>(wrow);
        acc[0] += u * w4.x;
        acc[1] += u * w4.y;
        acc[2] += u * w4.z;
        acc[3] += u * w4.w;
      }
    }
  }

  const int d = d0 + dloc;
  const float di = deg_inv[d];
  #pragma unroll
  for (int j = 0; j < VO; ++j) acc[j] *= di;

  const float* vs = vstage + dloc * FIN;
  for (int f = 0; f < FIN; f += 4) {
    const float4 v4 = *reinterpret_cast<const float4*>(vs + f);
    #pragma unroll
    for (int uu = 0; uu < 4; ++uu) {
      const float vv = (uu == 0) ? v4.x : (uu == 1) ? v4.y : (uu == 2) ? v4.z : v4.w;
      const float* rrow = root + (size_t)(f + uu) * HOUT + o0;
      if constexpr (VO == 2) {
        const float2 r2 = *reinterpret_cast<const float2*>(rrow);
        acc[0] += vv * r2.x;
        acc[1] += vv * r2.y;
      } else {
        const float4 r4 = *reinterpret_cast<const float4*>(rrow);
        acc[0] += vv * r4.x;
        acc[1] += vv * r4.y;
        acc[2] += vv * r4.z;
        acc[3] += vv * r4.w;
      }
    }
  }
  #pragma unroll
  for (int j = 0; j < VO; ++j) acc[j] += bias[o0 + j];
  #pragma unroll
  for (int j = 0; j < VO; ++j) outp[(size_t)d * HOUT + o0 + j] = acc[j];
}

__global__ __launch_bounds__(256) void conv_kernel(ConvP p, int t) {
  __shared__ float Ush[16 * (32 * KSP + 8)];  // 12928 f32, reused by both shapes
  __shared__ float vstage[512];
  const int slice = blockIdx.y;
  if (slice < 2) {
    // h-convs: FIN=64, NB=8 -> 2048 blocks
    conv_body<64, 8>(p.h, p.W[slice], p.root[slice], p.bias[slice], p.rp, p.esrc,
                     p.ewidx, p.ebasis, p.deg_inv, p.outs[slice], Ush, vstage);
  } else {
    // x-convs: FIN=32, NB=16 -> 1024 blocks
    if (blockIdx.x >= NNODE / 16) return;
    conv_body<32, 16>(p.xT + (size_t)t * NNODE * 32, p.W[slice], p.root[slice],
                      p.bias[slice], p.rp, p.esrc, p.ewidx, p.ebasis, p.deg_inv,
                      p.outs[slice], Ush, vstage);
  }
}

// ---------------- GRU pointwise ----------------

__device__ __forceinline__ float gru_cell(float xcr, float xcz, float xcn, float hr,
                                          float hz, float h) {
  const float r = 1.f / (1.f + __expf(-(xcr + hr)));
  const float z = 1.f / (1.f + __expf(-(xcz + hz)));
  const float n = 1.f - 2.f / (__expf(2.f * (xcn + r * hr)) + 1.f);  // tanh
  return (1.f - z) * n + z * h;
}

__global__ __launch_bounds__(256) void gru_kernel(const float* __restrict__ xcr,
                                                  const float* __restrict__ xcz,
                                                  const float* __restrict__ xcn,
                                                  const float* __restrict__ hrb,
                                                  const float* __restrict__ hzb,
                                                  float* __restrict__ h,
                                                  float* __restrict__ out,
                                                  float* __restrict__ out_last, int t) {
  const int i = blockIdx.x * 256 + threadIdx.x;   // over N*16 float4 groups
  if (i >= NNODE * 16) return;
  const int n = i >> 4;
  const int qo = (i & 15) << 2;
  const size_t base = (size_t)n * HOUT + qo;
  const float4 ar = *reinterpret_cast<const float4*>(xcr + base);
  const float4 az = *reinterpret_cast<const float4*>(xcz + base);
  const float4 an = *reinterpret_cast<const float4*>(xcn + base);
  const float4 r4 = *reinterpret_cast<const float4*>(hrb + base);
  const float4 z4 = *reinterpret_cast<const float4*>(hzb + base);
  const float4 h4 = *reinterpret_cast<const float4*>(h + base);
  float4 hn;
  hn.x = gru_cell(ar.x, az.x, an.x, r4.x, z4.x, h4.x);
  hn.y = gru_cell(ar.y, az.y, an.y, r4.y, z4.y, h4.y);
  hn.z = gru_cell(ar.z, az.z, an.z, r4.z, z4.z, h4.z);
  hn.w = gru_cell(ar.w, az.w, an.w, r4.w, z4.w, h4.w);
  *reinterpret_cast<float4*>(h + base) = hn;
  // layer_output (B,G,H,T): out[(n*64+o)*10 + t]
  float* ob = out + base * TSTEPS + t;
  ob[0] = hn.x;
  ob[10] = hn.y;
  ob[20] = hn.z;
  ob[30] = hn.w;
  if (out_last) *reinterpret_cast<float4*>(out_last + base) = hn;
}

// ---------------- host launch ----------------

extern "C" void kernel_launch(void* const* d_in, const int* in_sizes, int n_in,
                              void* d_out, int out_size, void* d_ws, size_t ws_size,
                              hipStream_t stream) {
  const float* x = (const float*)d_in[0];
  const int* ei = (const int*)d_in[1];
  const float* ea = (const float*)d_in[2];

  ConvP p;
  // d_in order: W_xr,root_xr,b_xr, W_hr,root_hr,b_hr, W_xz,root_xz,b_xz,
  //             W_hz,root_hz,b_hz, W_xn,root_xn,b_xn  (indices 3..17)
  p.W[0] = (const float*)d_in[6];  p.root[0] = (const float*)d_in[7];  p.bias[0] = (const float*)d_in[8];   // hr
  p.W[1] = (const float*)d_in[12]; p.root[1] = (const float*)d_in[13]; p.bias[1] = (const float*)d_in[14];  // hz
  p.W[2] = (const float*)d_in[3];  p.root[2] = (const float*)d_in[4];  p.bias[2] = (const float*)d_in[5];   // xr
  p.W[3] = (const float*)d_in[9];  p.root[3] = (const float*)d_in[10]; p.bias[3] = (const float*)d_in[11];  // xz
  p.W[4] = (const float*)d_in[15]; p.root[4] = (const float*)d_in[16]; p.bias[4] = (const float*)d_in[17];  // xn

  // workspace layout (all 16B aligned)
  char* w = (char*)d_ws;
  float* xT = (float*)w;              w += (size_t)TSTEPS * NNODE * 32 * 4;   // 21.0 MB
  float* xcr = (float*)w;             w += (size_t)NNODE * HOUT * 4;
  float* xcz = (float*)w;             w += (size_t)NNODE * HOUT * 4;
  float* xcn = (float*)w;             w += (size_t)NNODE * HOUT * 4;
  float* hrb = (float*)w;             w += (size_t)NNODE * HOUT * 4;
  float* hzb = (float*)w;             w += (size_t)NNODE * HOUT * 4;
  float* h = (float*)w;               w += (size_t)NNODE * HOUT * 4;
  float4* ebasis = (float4*)w;        w += (size_t)EDGES * 16;
  int* esrc = (int*)w;                w += (size_t)EDGES * 4;
  unsigned* ewidx = (unsigned*)w;     w += (size_t)EDGES * 4;
  int* degi = (int*)w;                w += (size_t)NNODE * 4;
  int* cursor = (int*)w;              w += (size_t)NNODE * 4;
  float* deg_inv = (float*)w;         w += (size_t)NNODE * 4;
  int* rp = (int*)w;                  w += (size_t)(NNODE + 4) * 4;

  p.h = h;
  p.xT = xT;
  p.rp = rp;
  p.esrc = esrc;
  p.ewidx = ewidx;
  p.ebasis = ebasis;
  p.deg_inv = deg_inv;
  p.outs[0] = hrb;
  p.outs[1] = hzb;
  p.outs[2] = xcr;
  p.outs[3] = xcz;
  p.outs[4] = xcn;

  hipMemsetAsync(degi, 0, (size_t)NNODE * 4, stream);
  hipMemsetAsync(cursor, 0, (size_t)NNODE * 4, stream);
  hipMemsetAsync(h, 0, (size_t)NNODE * HOUT * 4, stream);

  xpose_kernel<<<(NNODE * 32 + 255) / 256, 256, 0, stream>>>(x, xT);
  deg_kernel<<<(EDGES + 255) / 256, 256, 0, stream>>>(ei, degi);
  scan_kernel<<<1, 1024, 0, stream>>>(degi, rp, deg_inv);
  scatter_kernel<<<(EDGES + 255) / 256, 256, 0, stream>>>(ei, ea, rp, cursor, esrc,
                                                          ewidx, ebasis);

  float* out = (float*)d_out;
  float* out_last = out + (size_t)NNODE * HOUT * TSTEPS;

  for (int t = 0; t < TSTEPS; ++t) {
    conv_kernel<<<dim3(NNODE / 8, 5), 256, 0, stream>>>(p, t);
    gru_kernel<<<(NNODE * 16 + 255) / 256, 256, 0, stream>>>(
        xcr, xcz, xcn, hrb, hzb, h, out, (t == TSTEPS - 1) ? out_last : nullptr, t);
  }
}

// Round 2
// 1786.328 us; speedup vs baseline: 7.0380x; 7.0380x over previous
//
#include <hip/hip_runtime.h>
#include <hip/hip_bf16.h>

#define NNODE 16384
#define EDGES 262144
#define HOUT 64
#define TSTEPS 10
#define KT_H 1664   // 25*64 + 64 (root appended)
#define KP_H 1672   // +8 bf16 pad for LDS bank spread
#define KT_X 832    // 25*32 + 32
#define KP_X 840
#define NB 16

typedef __attribute__((ext_vector_type(8))) short bf16x8;
typedef __attribute__((ext_vector_type(4))) float f32x4;
typedef unsigned short u16;

__device__ __forceinline__ u16 f2b(float x) {
  __hip_bfloat16 b = __float2bfloat16(x);
  return *reinterpret_cast<const u16*>(&b);
}

// ---------------- prep kernels ----------------

// x: (N, 32, T) -> xT: (T, N, 32)
__global__ __launch_bounds__(256) void xpose_kernel(const float* __restrict__ x,
                                                    float* __restrict__ xT) {
  const int i = blockIdx.x * 256 + threadIdx.x;   // i = n*32 + f
  if (i >= NNODE * 32) return;
  const float* src = x + (size_t)i * TSTEPS;
  #pragma unroll
  for (int t = 0; t < TSTEPS; ++t)
    xT[(size_t)t * NNODE * 32 + i] = src[t];
}

__global__ __launch_bounds__(256) void deg_kernel(const int* __restrict__ ei,
                                                  int* __restrict__ degi) {
  const int e = blockIdx.x * 256 + threadIdx.x;
  if (e >= EDGES) return;
  atomicAdd(&degi[ei[EDGES + e]], 1);
}

__global__ __launch_bounds__(1024) void scan_kernel(const int* __restrict__ degi,
                                                    int* __restrict__ rp,
                                                    float* __restrict__ deg_inv) {
  __shared__ int sh[1024];
  const int tid = threadIdx.x;
  const int base = tid * 16;
  int loc[16];
  int sum = 0;
  #pragma unroll
  for (int i = 0; i < 16; ++i) { loc[i] = degi[base + i]; sum += loc[i]; }
  sh[tid] = sum;
  __syncthreads();
  for (int off = 1; off < 1024; off <<= 1) {
    int v = 0;
    if (tid >= off) v = sh[tid - off];
    __syncthreads();
    if (tid >= off) sh[tid] += v;
    __syncthreads();
  }
  int ex = sh[tid] - sum;
  #pragma unroll
  for (int i = 0; i < 16; ++i) {
    rp[base + i] = ex;
    ex += loc[i];
    deg_inv[base + i] = 1.f / (float)max(loc[i], 1);
  }
  if (tid == 1023) rp[NNODE] = ex;
}

// CSR scatter; emeta = src | (cell<<24), cell = k0 + 4*k1
__global__ __launch_bounds__(256) void scatter_kernel(const int* __restrict__ ei,
                                                      const float* __restrict__ ea,
                                                      const int* __restrict__ rp,
                                                      int* __restrict__ cursor,
                                                      int* __restrict__ emeta,
                                                      float4* __restrict__ ebasis) {
  const int e = blockIdx.x * 256 + threadIdx.x;
  if (e >= EDGES) return;
  const int s = ei[e];
  const int d = ei[EDGES + e];
  const int pos = rp[d] + atomicAdd(&cursor[d], 1);
  const float a0 = ea[2 * e], a1 = ea[2 * e + 1];
  const float f0 = a0 * 4.f, f1 = a1 * 4.f;
  const float k0f = fminf(fmaxf(floorf(f0), 0.f), 3.f);
  const float k1f = fminf(fmaxf(floorf(f1), 0.f), 3.f);
  const float t0 = f0 - k0f, t1 = f1 - k1f;
  const int cell = (int)k0f + 4 * (int)k1f;
  emeta[pos] = s | (cell << 24);
  float4 b;
  b.x = (1.f - t0) * (1.f - t1);   // (k0,   k1)
  b.y = (1.f - t0) * t1;           // (k0,   k1+1)
  b.z = t0 * (1.f - t1);           // (k0+1, k1)
  b.w = t0 * t1;                   // (k0+1, k1+1)
  ebasis[pos] = b;
}

// W (KSPFIN x 64) + root appended -> W_T bf16 [64][KT]
__global__ __launch_bounds__(256) void wprep_kernel(const float* __restrict__ W,
                                                    const float* __restrict__ root,
                                                    u16* __restrict__ out,
                                                    int kspfin, int kt) {
  const int i = blockIdx.x * 256 + threadIdx.x;
  if (i >= 64 * kt) return;
  const int o = i / kt, kf = i % kt;
  const float v = (kf < kspfin) ? W[(size_t)kf * 64 + o]
                                : root[(size_t)(kf - kspfin) * 64 + o];
  out[(size_t)o * kt + kf] = f2b(v);
}

// ---------------- fused conv+GRU step ----------------

struct GP {
  const float* xT;
  const float* h_cur;
  float* h_next;
  const int* rp;
  const int* emeta;
  const float4* ebasis;
  const float* deg_inv;
  const u16* WhrT; const u16* WhzT;
  const u16* WxrT; const u16* WxzT; const u16* WxnT;
  const float* b_hr; const float* b_hz;
  const float* b_xr; const float* b_xz; const float* b_xn;
  float* out;
  float* out_last;
};

#define CELL_CASE(K0, K1)                                   \
  case ((K0) + 4 * (K1)): {                                 \
    accH[(K0) + 5 * (K1)]     += bs.x * hvh;                \
    accH[(K0) + 5 * (K1) + 5] += bs.y * hvh;                \
    accH[(K0) + 5 * (K1) + 1] += bs.z * hvh;                \
    accH[(K0) + 5 * (K1) + 6] += bs.w * hvh;                \
    accX[(K0) + 5 * (K1)]     += bs.x * hvx;                \
    accX[(K0) + 5 * (K1) + 5] += bs.y * hvx;                \
    accX[(K0) + 5 * (K1) + 1] += bs.z * hvx;                \
    accX[(K0) + 5 * (K1) + 6] += bs.w * hvx;                \
  } break;

__global__ __launch_bounds__(256) void gcgru_step(GP p, int t) {
  __shared__ __align__(16) u16 UH[NB * KP_H];   // 53504 B
  __shared__ __align__(16) u16 UX[NB * KP_X];   // 26880 B
  const int tid = threadIdx.x;
  const int wave = tid >> 6, lane = tid & 63;
  const int d0 = blockIdx.x * NB;
  const float* __restrict__ xTt = p.xT + (size_t)t * NNODE * 32;
  const int fl32 = lane & 31;

  // ---- phase 2: build U_h and U_x rows (4 nodes per wave, sequential) ----
  for (int nn = 0; nn < 4; ++nn) {
    const int d = d0 + wave * 4 + nn;
    float accH[25], accX[25];
    #pragma unroll
    for (int k = 0; k < 25; ++k) { accH[k] = 0.f; accX[k] = 0.f; }
    const int e0 = p.rp[d], e1 = p.rp[d + 1];
    int m0 = 0, m1 = 0;
    float4 b0 = {0, 0, 0, 0}, b1 = {0, 0, 0, 0};
    float hvh = 0.f, hvx = 0.f;
    if (e0 < e1) { m0 = p.emeta[e0]; b0 = p.ebasis[e0]; }
    if (e0 + 1 < e1) { m1 = p.emeta[e0 + 1]; b1 = p.ebasis[e0 + 1]; }
    if (e0 < e1) {
      const int s = m0 & 0xffff;
      hvh = p.h_cur[(size_t)s * 64 + lane];
      hvx = xTt[(size_t)s * 32 + fl32];
    }
    for (int e = e0; e < e1; ++e) {
      // prefetch meta 2 ahead, gather 1 ahead
      int m2 = 0;
      float4 b2 = {0, 0, 0, 0};
      if (e + 2 < e1) { m2 = p.emeta[e + 2]; b2 = p.ebasis[e + 2]; }
      float hvh1 = 0.f, hvx1 = 0.f;
      if (e + 1 < e1) {
        const int s1 = m1 & 0xffff;
        hvh1 = p.h_cur[(size_t)s1 * 64 + lane];
        hvx1 = xTt[(size_t)s1 * 32 + fl32];
      }
      const int cell = __builtin_amdgcn_readfirstlane(((unsigned)m0) >> 24);
      const float4 bs = b0;
      switch (cell) {
        CELL_CASE(0, 0) CELL_CASE(1, 0) CELL_CASE(2, 0) CELL_CASE(3, 0)
        CELL_CASE(0, 1) CELL_CASE(1, 1) CELL_CASE(2, 1) CELL_CASE(3, 1)
        CELL_CASE(0, 2) CELL_CASE(1, 2) CELL_CASE(2, 2) CELL_CASE(3, 2)
        CELL_CASE(0, 3) CELL_CASE(1, 3) CELL_CASE(2, 3) CELL_CASE(3, 3)
      }
      m0 = m1; b0 = b1; m1 = m2; b1 = b2; hvh = hvh1; hvx = hvx1;
    }
    // write U rows (deg_inv folded into the agg part; root appended unscaled)
    const float di = p.deg_inv[d];
    u16* uh = UH + (size_t)(wave * 4 + nn) * KP_H;
    #pragma unroll
    for (int k = 0; k < 25; ++k) uh[k * 64 + lane] = f2b(accH[k] * di);
    uh[1600 + lane] = f2b(p.h_cur[(size_t)d * 64 + lane]);
    if (lane < 32) {
      u16* ux = UX + (size_t)(wave * 4 + nn) * KP_X;
      #pragma unroll
      for (int k = 0; k < 25; ++k) ux[k * 32 + lane] = f2b(accX[k] * di);
      ux[800 + lane] = f2b(xTt[(size_t)d * 32 + lane]);
    }
  }
  __syncthreads();

  // ---- phase 3: MFMA contractions; wave = o-tile ----
  const int col = lane & 15, q = lane >> 4;
  const int o = wave * 16 + col;
  f32x4 ahr, ahz, axr, axz, axn;
  { const float b = p.b_hr[o]; ahr = f32x4{b, b, b, b}; }
  { const float b = p.b_hz[o]; ahz = f32x4{b, b, b, b}; }
  { const float b = p.b_xr[o]; axr = f32x4{b, b, b, b}; }
  { const float b = p.b_xz[o]; axz = f32x4{b, b, b, b}; }
  { const float b = p.b_xn[o]; axn = f32x4{b, b, b, b}; }

  const u16* aH = UH + (size_t)col * KP_H + 8 * q;
  const u16* bHr = p.WhrT + (size_t)o * KT_H + 8 * q;
  const u16* bHz = p.WhzT + (size_t)o * KT_H + 8 * q;
  #pragma unroll 4
  for (int ks = 0; ks < KT_H / 32; ++ks) {
    const bf16x8 a = *reinterpret_cast<const bf16x8*>(aH + ks * 32);
    const bf16x8 wr = *reinterpret_cast<const bf16x8*>(bHr + ks * 32);
    const bf16x8 wz = *reinterpret_cast<const bf16x8*>(bHz + ks * 32);
    ahr = __builtin_amdgcn_mfma_f32_16x16x32_bf16(a, wr, ahr, 0, 0, 0);
    ahz = __builtin_amdgcn_mfma_f32_16x16x32_bf16(a, wz, ahz, 0, 0, 0);
  }
  const u16* aX = UX + (size_t)col * KP_X + 8 * q;
  const u16* bXr = p.WxrT + (size_t)o * KT_X + 8 * q;
  const u16* bXz = p.WxzT + (size_t)o * KT_X + 8 * q;
  const u16* bXn = p.WxnT + (size_t)o * KT_X + 8 * q;
  #pragma unroll 4
  for (int ks = 0; ks < KT_X / 32; ++ks) {
    const bf16x8 a = *reinterpret_cast<const bf16x8*>(aX + ks * 32);
    const bf16x8 wr = *reinterpret_cast<const bf16x8*>(bXr + ks * 32);
    const bf16x8 wz = *reinterpret_cast<const bf16x8*>(bXz + ks * 32);
    const bf16x8 wn = *reinterpret_cast<const bf16x8*>(bXn + ks * 32);
    axr = __builtin_amdgcn_mfma_f32_16x16x32_bf16(a, wr, axr, 0, 0, 0);
    axz = __builtin_amdgcn_mfma_f32_16x16x32_bf16(a, wz, axz, 0, 0, 0);
    axn = __builtin_amdgcn_mfma_f32_16x16x32_bf16(a, wn, axn, 0, 0, 0);
  }

  // ---- GRU epilogue: C layout col=lane&15, row=(lane>>4)*4+reg ----
  #pragma unroll
  for (int j = 0; j < 4; ++j) {
    const int node = d0 + q * 4 + j;
    const float hrv = ahr[j], hzv = ahz[j];
    const float xrv = axr[j], xzv = axz[j], xnv = axn[j];
    const float r = 1.f / (1.f + __expf(-(xrv + hrv)));
    const float z = 1.f / (1.f + __expf(-(xzv + hzv)));
    const float ng = 1.f - 2.f / (__expf(2.f * (xnv + r * hrv)) + 1.f);  // tanh
    const float hp = p.h_cur[(size_t)node * 64 + o];
    const float hn = (1.f - z) * ng + z * hp;
    p.h_next[(size_t)node * 64 + o] = hn;
    p.out[((size_t)node * 64 + o) * TSTEPS + t] = hn;
    if (p.out_last) p.out_last[(size_t)node * 64 + o] = hn;
  }
}

// ---------------- host launch ----------------

extern "C" void kernel_launch(void* const* d_in, const int* in_sizes, int n_in,
                              void* d_out, int out_size, void* d_ws, size_t ws_size,
                              hipStream_t stream) {
  const float* x = (const float*)d_in[0];
  const int* ei = (const int*)d_in[1];
  const float* ea = (const float*)d_in[2];
  // d_in: 3..17 = W_xr,root_xr,b_xr, W_hr,root_hr,b_hr, W_xz,root_xz,b_xz,
  //               W_hz,root_hz,b_hz, W_xn,root_xn,b_xn
  const float* W_xr = (const float*)d_in[3];
  const float* root_xr = (const float*)d_in[4];
  const float* b_xr = (const float*)d_in[5];
  const float* W_hr = (const float*)d_in[6];
  const float* root_hr = (const float*)d_in[7];
  const float* b_hr = (const float*)d_in[8];
  const float* W_xz = (const float*)d_in[9];
  const float* root_xz = (const float*)d_in[10];
  const float* b_xz = (const float*)d_in[11];
  const float* W_hz = (const float*)d_in[12];
  const float* root_hz = (const float*)d_in[13];
  const float* b_hz = (const float*)d_in[14];
  const float* W_xn = (const float*)d_in[15];
  const float* root_xn = (const float*)d_in[16];
  const float* b_xn = (const float*)d_in[17];

  char* w = (char*)d_ws;
  float* xT = (float*)w;      w += (size_t)TSTEPS * NNODE * 32 * 4;   // 21.0 MB
  float* h0 = (float*)w;      w += (size_t)NNODE * HOUT * 4;
  float* h1 = (float*)w;      w += (size_t)NNODE * HOUT * 4;
  float4* ebasis = (float4*)w; w += (size_t)EDGES * 16;
  int* emeta = (int*)w;       w += (size_t)EDGES * 4;
  u16* WhrT = (u16*)w;        w += (size_t)64 * KT_H * 2;
  u16* WhzT = (u16*)w;        w += (size_t)64 * KT_H * 2;
  u16* WxrT = (u16*)w;        w += (size_t)64 * KT_X * 2;
  u16* WxzT = (u16*)w;        w += (size_t)64 * KT_X * 2;
  u16* WxnT = (u16*)w;        w += (size_t)64 * KT_X * 2;
  int* degi = (int*)w;        w += (size_t)NNODE * 4;
  int* cursor = (int*)w;      w += (size_t)NNODE * 4;
  float* deg_inv = (float*)w; w += (size_t)NNODE * 4;
  int* rp = (int*)w;          w += (size_t)(NNODE + 4) * 4;

  hipMemsetAsync(degi, 0, (size_t)NNODE * 4, stream);
  hipMemsetAsync(cursor, 0, (size_t)NNODE * 4, stream);
  hipMemsetAsync(h0, 0, (size_t)NNODE * HOUT * 4, stream);

  xpose_kernel<<<(NNODE * 32 + 255) / 256, 256, 0, stream>>>(x, xT);
  deg_kernel<<<(EDGES + 255) / 256, 256, 0, stream>>>(ei, degi);
  scan_kernel<<<1, 1024, 0, stream>>>(degi, rp, deg_inv);
  scatter_kernel<<<(EDGES + 255) / 256, 256, 0, stream>>>(ei, ea, rp, cursor, emeta,
                                                          ebasis);
  const int gH = (64 * KT_H + 255) / 256;
  const int gX = (64 * KT_X + 255) / 256;
  wprep_kernel<<<gH, 256, 0, stream>>>(W_hr, root_hr, WhrT, 1600, KT_H);
  wprep_kernel<<<gH, 256, 0, stream>>>(W_hz, root_hz, WhzT, 1600, KT_H);
  wprep_kernel<<<gX, 256, 0, stream>>>(W_xr, root_xr, WxrT, 800, KT_X);
  wprep_kernel<<<gX, 256, 0, stream>>>(W_xz, root_xz, WxzT, 800, KT_X);
  wprep_kernel<<<gX, 256, 0, stream>>>(W_xn, root_xn, WxnT, 800, KT_X);

  float* out = (float*)d_out;
  float* out_last = out + (size_t)NNODE * HOUT * TSTEPS;

  GP p;
  p.xT = xT;
  p.rp = rp;
  p.emeta = emeta;
  p.ebasis = ebasis;
  p.deg_inv = deg_inv;
  p.WhrT = WhrT; p.WhzT = WhzT;
  p.WxrT = WxrT; p.WxzT = WxzT; p.WxnT = WxnT;
  p.b_hr = b_hr; p.b_hz = b_hz;
  p.b_xr = b_xr; p.b_xz = b_xz; p.b_xn = b_xn;
  p.out = out;

  float* ha = h0;
  float* hb = h1;
  for (int t = 0; t < TSTEPS; ++t) {
    p.h_cur = ha;
    p.h_next = hb;
    p.out_last = (t == TSTEPS - 1) ? out_last : nullptr;
    gcgru_step<<<NNODE / NB, 256, 0, stream>>>(p, t);
    float* tmp = ha; ha = hb; hb = tmp;
  }
}

// Round 3
// 1723.559 us; speedup vs baseline: 7.2943x; 1.0364x over previous
//
#include <hip/hip_runtime.h>
#include <hip/hip_bf16.h>
#include <hip/hip_fp16.h>

#define NNODE 16384
#define EDGES 262144
#define HOUT 64
#define TSTEPS 10
#define KT_H 1664   // 25*64 + 64 (root appended)
#define KT_X 832    // 25*32 + 32
#define NB 16       // nodes per block, step kernel
#define NBX 32      // nodes per block, xc kernel

typedef __attribute__((ext_vector_type(8))) short bf16x8;
typedef __attribute__((ext_vector_type(4))) float f32x4;
typedef unsigned short u16;

__device__ __forceinline__ u16 f2b(float x) {
  __hip_bfloat16 b = __float2bfloat16(x);
  return *reinterpret_cast<const u16*>(&b);
}
__device__ __forceinline__ float b2f(u16 v) {
  union { unsigned u; float f; } c;
  c.u = ((unsigned)v) << 16;
  return c.f;
}

// ---------------- prep kernels ----------------

// x: (N, 32, T) f32 -> xTb: (T, N, 32) bf16
__global__ __launch_bounds__(256) void xpose_kernel(const float* __restrict__ x,
                                                    u16* __restrict__ xTb) {
  const int i = blockIdx.x * 256 + threadIdx.x;   // i = n*32 + f
  if (i >= NNODE * 32) return;
  const float* src = x + (size_t)i * TSTEPS;
  #pragma unroll
  for (int t = 0; t < TSTEPS; ++t)
    xTb[(size_t)t * NNODE * 32 + i] = f2b(src[t]);
}

__global__ __launch_bounds__(256) void deg_kernel(const int* __restrict__ ei,
                                                  int* __restrict__ degi) {
  const int e = blockIdx.x * 256 + threadIdx.x;
  if (e >= EDGES) return;
  atomicAdd(&degi[ei[EDGES + e]], 1);
}

__global__ __launch_bounds__(1024) void scan_kernel(const int* __restrict__ degi,
                                                    int* __restrict__ rp,
                                                    float* __restrict__ deg_inv) {
  __shared__ int sh[1024];
  const int tid = threadIdx.x;
  const int base = tid * 16;
  int loc[16];
  int sum = 0;
  #pragma unroll
  for (int i = 0; i < 16; ++i) { loc[i] = degi[base + i]; sum += loc[i]; }
  sh[tid] = sum;
  __syncthreads();
  for (int off = 1; off < 1024; off <<= 1) {
    int v = 0;
    if (tid >= off) v = sh[tid - off];
    __syncthreads();
    if (tid >= off) sh[tid] += v;
    __syncthreads();
  }
  int ex = sh[tid] - sum;
  #pragma unroll
  for (int i = 0; i < 16; ++i) {
    rp[base + i] = ex;
    ex += loc[i];
    deg_inv[base + i] = 1.f / (float)max(loc[i], 1);
  }
  if (tid == 1023) rp[NNODE] = ex;
}

// CSR scatter; emeta = src | (cell<<24), cell = k0 + 4*k1
__global__ __launch_bounds__(256) void scatter_kernel(const int* __restrict__ ei,
                                                      const float* __restrict__ ea,
                                                      const int* __restrict__ rp,
                                                      int* __restrict__ cursor,
                                                      int* __restrict__ emeta,
                                                      float4* __restrict__ ebasis) {
  const int e = blockIdx.x * 256 + threadIdx.x;
  if (e >= EDGES) return;
  const int s = ei[e];
  const int d = ei[EDGES + e];
  const int pos = rp[d] + atomicAdd(&cursor[d], 1);
  const float a0 = ea[2 * e], a1 = ea[2 * e + 1];
  const float f0 = a0 * 4.f, f1 = a1 * 4.f;
  const float k0f = fminf(fmaxf(floorf(f0), 0.f), 3.f);
  const float k1f = fminf(fmaxf(floorf(f1), 0.f), 3.f);
  const float t0 = f0 - k0f, t1 = f1 - k1f;
  const int cell = (int)k0f + 4 * (int)k1f;
  emeta[pos] = s | (cell << 24);
  float4 b;
  b.x = (1.f - t0) * (1.f - t1);   // (k0,   k1)
  b.y = (1.f - t0) * t1;           // (k0,   k1+1)
  b.z = t0 * (1.f - t1);           // (k0+1, k1)
  b.w = t0 * t1;                   // (k0+1, k1+1)
  ebasis[pos] = b;
}

// W (KSPFIN x 64) + root appended -> W_T bf16 [64][KT]
__global__ __launch_bounds__(256) void wprep_kernel(const float* __restrict__ W,
                                                    const float* __restrict__ root,
                                                    u16* __restrict__ out,
                                                    int kspfin, int kt) {
  const int i = blockIdx.x * 256 + threadIdx.x;
  if (i >= 64 * kt) return;
  const int o = i / kt, kf = i % kt;
  const float v = (kf < kspfin) ? W[(size_t)kf * 64 + o]
                                : root[(size_t)(kf - kspfin) * 64 + o];
  out[(size_t)o * kt + kf] = f2b(v);
}

// ---------------- batch x-conv kernel (all t, all 3 x-convs) ----------------

struct XP {
  const u16* xTb;
  const int* rp;
  const int* emeta;
  const float4* ebasis;
  const float* deg_inv;
  const u16* WxrT; const u16* WxzT; const u16* WxnT;
  const float* b_xr; const float* b_xz; const float* b_xn;
  __half* xcr; __half* xcz; __half* xcn;
};

#define CELL_CASE_X(K0, K1)                            \
  case ((K0) + 4 * (K1)):                              \
    accX[(K0) + 5 * (K1)]     += bs.x * xv;            \
    accX[(K0) + 5 * (K1) + 5] += bs.y * xv;            \
    accX[(K0) + 5 * (K1) + 1] += bs.z * xv;            \
    accX[(K0) + 5 * (K1) + 6] += bs.w * xv;            \
    break;

__global__ __launch_bounds__(256, 3) void xc_kernel(XP p) {
  __shared__ __align__(16) u16 UX[NBX * KT_X];   // 53248 B -> 3 blocks/CU
  const int tid = threadIdx.x;
  const int wave = tid >> 6, lane = tid & 63;
  const int t = blockIdx.y;
  const int d0 = blockIdx.x * NBX;
  const u16* __restrict__ xb = p.xTb + (size_t)t * NNODE * 32;
  const int fl = lane & 31;

  // phase 2: 8 nodes per wave (lanes 32-63 duplicate lanes 0-31's features)
  for (int nn = 0; nn < 8; ++nn) {
    const int dloc = wave * 8 + nn;
    const int d = d0 + dloc;
    const int e0 = __builtin_amdgcn_readfirstlane(p.rp[d]);
    const int e1 = __builtin_amdgcn_readfirstlane(p.rp[d + 1]);
    float accX[25];
    #pragma unroll
    for (int k = 0; k < 25; ++k) accX[k] = 0.f;
    int m0 = p.emeta[e0], m1 = p.emeta[e0 + 1], m2 = p.emeta[e0 + 2];
    float4 b0 = p.ebasis[e0], b1 = p.ebasis[e0 + 1], b2 = p.ebasis[e0 + 2];
    float v0 = b2f(xb[(size_t)(m0 & 0x3fff) * 32 + fl]);
    float v1 = b2f(xb[(size_t)(m1 & 0x3fff) * 32 + fl]);
    float v2 = b2f(xb[(size_t)(m2 & 0x3fff) * 32 + fl]);
    for (int e = e0; e < e1; ++e) {
      const int m3 = p.emeta[e + 3];
      const float4 b3 = p.ebasis[e + 3];
      const float v3 = b2f(xb[(size_t)(m3 & 0x3fff) * 32 + fl]);
      const int cell = __builtin_amdgcn_readfirstlane(((unsigned)m0) >> 24);
      const float4 bs = b0;
      const float xv = v0;
      switch (cell) {
        CELL_CASE_X(0, 0) CELL_CASE_X(1, 0) CELL_CASE_X(2, 0) CELL_CASE_X(3, 0)
        CELL_CASE_X(0, 1) CELL_CASE_X(1, 1) CELL_CASE_X(2, 1) CELL_CASE_X(3, 1)
        CELL_CASE_X(0, 2) CELL_CASE_X(1, 2) CELL_CASE_X(2, 2) CELL_CASE_X(3, 2)
        CELL_CASE_X(0, 3) CELL_CASE_X(1, 3) CELL_CASE_X(2, 3) CELL_CASE_X(3, 3)
      }
      m0 = m1; m1 = m2; m2 = m3;
      b0 = b1; b1 = b2; b2 = b3;
      v0 = v1; v1 = v2; v2 = v3;
    }
    if (lane < 32) {
      const float di = p.deg_inv[d];
      u16* ux = UX + dloc * KT_X;
      const int sw = (dloc & 7) << 3;
      #pragma unroll
      for (int k = 0; k < 25; ++k) ux[(k * 32 + lane) ^ sw] = f2b(accX[k] * di);
      ux[(800 + lane) ^ sw] = xb[(size_t)d * 32 + lane];
    }
  }
  __syncthreads();

  // phase 3: 2 node-subtiles x 3 convs, W frags loaded once per ks
  const int col = lane & 15, q = lane >> 4;
  const int o = wave * 16 + col;
  const int swc = (col & 7) << 3;
  f32x4 a0r, a0z, a0n, a1r, a1z, a1n;
  { const float b = p.b_xr[o]; a0r = f32x4{b, b, b, b}; a1r = a0r; }
  { const float b = p.b_xz[o]; a0z = f32x4{b, b, b, b}; a1z = a0z; }
  { const float b = p.b_xn[o]; a0n = f32x4{b, b, b, b}; a1n = a0n; }
  const u16* bXr = p.WxrT + (size_t)o * KT_X + 8 * q;
  const u16* bXz = p.WxzT + (size_t)o * KT_X + 8 * q;
  const u16* bXn = p.WxnT + (size_t)o * KT_X + 8 * q;
  #pragma unroll 2
  for (int ks = 0; ks < KT_X / 32; ++ks) {
    const bf16x8 wr = *reinterpret_cast<const bf16x8*>(bXr + ks * 32);
    const bf16x8 wz = *reinterpret_cast<const bf16x8*>(bXz + ks * 32);
    const bf16x8 wn = *reinterpret_cast<const bf16x8*>(bXn + ks * 32);
    const int ofs = (ks * 32 + q * 8) ^ swc;
    const bf16x8 a0 = *reinterpret_cast<const bf16x8*>(UX + col * KT_X + ofs);
    const bf16x8 a1 = *reinterpret_cast<const bf16x8*>(UX + (col + 16) * KT_X + ofs);
    a0r = __builtin_amdgcn_mfma_f32_16x16x32_bf16(a0, wr, a0r, 0, 0, 0);
    a0z = __builtin_amdgcn_mfma_f32_16x16x32_bf16(a0, wz, a0z, 0, 0, 0);
    a0n = __builtin_amdgcn_mfma_f32_16x16x32_bf16(a0, wn, a0n, 0, 0, 0);
    a1r = __builtin_amdgcn_mfma_f32_16x16x32_bf16(a1, wr, a1r, 0, 0, 0);
    a1z = __builtin_amdgcn_mfma_f32_16x16x32_bf16(a1, wz, a1z, 0, 0, 0);
    a1n = __builtin_amdgcn_mfma_f32_16x16x32_bf16(a1, wn, a1n, 0, 0, 0);
  }

  // epilogue: C layout col=lane&15, row=(lane>>4)*4+reg
  #pragma unroll
  for (int j = 0; j < 4; ++j) {
    const int r0 = d0 + q * 4 + j;
    const int r1 = r0 + 16;
    const size_t i0 = (size_t)t * NNODE * 64 + (size_t)r0 * 64 + o;
    const size_t i1 = (size_t)t * NNODE * 64 + (size_t)r1 * 64 + o;
    p.xcr[i0] = __float2half(a0r[j]);
    p.xcz[i0] = __float2half(a0z[j]);
    p.xcn[i0] = __float2half(a0n[j]);
    p.xcr[i1] = __float2half(a1r[j]);
    p.xcz[i1] = __float2half(a1z[j]);
    p.xcn[i1] = __float2half(a1n[j]);
  }
}

// ---------------- sequential step kernel (h-convs + GRU) ----------------

struct GP {
  const float* h_cur;
  const u16* h_curb;
  float* h_next;
  u16* h_nextb;
  const int* rp;
  const int* emeta;
  const float4* ebasis;
  const float* deg_inv;
  const u16* WhrT; const u16* WhzT;
  const float* b_hr; const float* b_hz;
  const __half* xcr; const __half* xcz; const __half* xcn;
  u16* hs;
};

#define CELL_CASE_H(K0, K1)                            \
  case ((K0) + 4 * (K1)):                              \
    accH[(K0) + 5 * (K1)]     += bs.x * hv;            \
    accH[(K0) + 5 * (K1) + 5] += bs.y * hv;            \
    accH[(K0) + 5 * (K1) + 1] += bs.z * hv;            \
    accH[(K0) + 5 * (K1) + 6] += bs.w * hv;            \
    break;

__global__ __launch_bounds__(256, 3) void gcgru_step(GP p, int t) {
  __shared__ __align__(16) u16 UH[NB * KT_H];   // 53248 B -> 3 blocks/CU
  const int tid = threadIdx.x;
  const int wave = tid >> 6, lane = tid & 63;
  const int d0 = blockIdx.x * NB;

  // phase 2: 4 nodes per wave, depth-3 pipelined gather
  for (int nn = 0; nn < 4; ++nn) {
    const int dloc = wave * 4 + nn;
    const int d = d0 + dloc;
    const int e0 = __builtin_amdgcn_readfirstlane(p.rp[d]);
    const int e1 = __builtin_amdgcn_readfirstlane(p.rp[d + 1]);
    float accH[25];
    #pragma unroll
    for (int k = 0; k < 25; ++k) accH[k] = 0.f;
    int m0 = p.emeta[e0], m1 = p.emeta[e0 + 1], m2 = p.emeta[e0 + 2];
    float4 b0 = p.ebasis[e0], b1 = p.ebasis[e0 + 1], b2 = p.ebasis[e0 + 2];
    float v0 = b2f(p.h_curb[(size_t)(m0 & 0x3fff) * 64 + lane]);
    float v1 = b2f(p.h_curb[(size_t)(m1 & 0x3fff) * 64 + lane]);
    float v2 = b2f(p.h_curb[(size_t)(m2 & 0x3fff) * 64 + lane]);
    for (int e = e0; e < e1; ++e) {
      const int m3 = p.emeta[e + 3];
      const float4 b3 = p.ebasis[e + 3];
      const float v3 = b2f(p.h_curb[(size_t)(m3 & 0x3fff) * 64 + lane]);
      const int cell = __builtin_amdgcn_readfirstlane(((unsigned)m0) >> 24);
      const float4 bs = b0;
      const float hv = v0;
      switch (cell) {
        CELL_CASE_H(0, 0) CELL_CASE_H(1, 0) CELL_CASE_H(2, 0) CELL_CASE_H(3, 0)
        CELL_CASE_H(0, 1) CELL_CASE_H(1, 1) CELL_CASE_H(2, 1) CELL_CASE_H(3, 1)
        CELL_CASE_H(0, 2) CELL_CASE_H(1, 2) CELL_CASE_H(2, 2) CELL_CASE_H(3, 2)
        CELL_CASE_H(0, 3) CELL_CASE_H(1, 3) CELL_CASE_H(2, 3) CELL_CASE_H(3, 3)
      }
      m0 = m1; m1 = m2; m2 = m3;
      b0 = b1; b1 = b2; b2 = b3;
      v0 = v1; v1 = v2; v2 = v3;
    }
    const float di = p.deg_inv[d];
    u16* uh = UH + dloc * KT_H;
    const int sw = (dloc & 7) << 3;
    #pragma unroll
    for (int k = 0; k < 25; ++k) uh[(k * 64 + lane) ^ sw] = f2b(accH[k] * di);
    uh[(1600 + lane) ^ sw] = p.h_curb[(size_t)d * 64 + lane];
  }
  __syncthreads();

  // phase 3: hr/hz MFMA chains
  const int col = lane & 15, q = lane >> 4;
  const int o = wave * 16 + col;
  const int swc = (col & 7) << 3;
  f32x4 ahr, ahz;
  { const float b = p.b_hr[o]; ahr = f32x4{b, b, b, b}; }
  { const float b = p.b_hz[o]; ahz = f32x4{b, b, b, b}; }
  const u16* bHr = p.WhrT + (size_t)o * KT_H + 8 * q;
  const u16* bHz = p.WhzT + (size_t)o * KT_H + 8 * q;
  #pragma unroll 4
  for (int ks = 0; ks < KT_H / 32; ++ks) {
    const bf16x8 a =
        *reinterpret_cast<const bf16x8*>(UH + col * KT_H + ((ks * 32 + q * 8) ^ swc));
    const bf16x8 wr = *reinterpret_cast<const bf16x8*>(bHr + ks * 32);
    const bf16x8 wz = *reinterpret_cast<const bf16x8*>(bHz + ks * 32);
    ahr = __builtin_amdgcn_mfma_f32_16x16x32_bf16(a, wr, ahr, 0, 0, 0);
    ahz = __builtin_amdgcn_mfma_f32_16x16x32_bf16(a, wz, ahz, 0, 0, 0);
  }

  // GRU epilogue: C layout col=lane&15, row=(lane>>4)*4+reg
  #pragma unroll
  for (int j = 0; j < 4; ++j) {
    const int node = d0 + q * 4 + j;
    const size_t idx = (size_t)node * 64 + o;
    const size_t tix = (size_t)t * NNODE * 64 + idx;
    const float xrv = __half2float(p.xcr[tix]);
    const float xzv = __half2float(p.xcz[tix]);
    const float xnv = __half2float(p.xcn[tix]);
    const float hrv = ahr[j], hzv = ahz[j];
    const float r = 1.f / (1.f + __expf(-(xrv + hrv)));
    const float z = 1.f / (1.f + __expf(-(xzv + hzv)));
    const float ng = 1.f - 2.f / (__expf(2.f * (xnv + r * hrv)) + 1.f);  // tanh
    const float hp = p.h_cur[idx];
    const float hn = (1.f - z) * ng + z * hp;
    p.h_next[idx] = hn;
    const u16 hb = f2b(hn);
    p.h_nextb[idx] = hb;
    p.hs[tix] = hb;
  }
}

// ---------------- finalize: hs [t][n][o] bf16 -> out (B,G,H,T) f32 ----------------

__global__ __launch_bounds__(256) void finalize_kernel(const u16* __restrict__ hs,
                                                       float* __restrict__ out,
                                                       float* __restrict__ out_last) {
  const int i = blockIdx.x * 256 + threadIdx.x;   // i = n*64 + o
  if (i >= NNODE * 64) return;
  float* ob = out + (size_t)(i >> 6) * 640 + (size_t)(i & 63) * 10;
  #pragma unroll
  for (int t = 0; t < TSTEPS; ++t)
    ob[t] = b2f(hs[(size_t)t * NNODE * 64 + i]);
  out_last[i] = b2f(hs[(size_t)9 * NNODE * 64 + i]);
}

// ---------------- host launch ----------------

extern "C" void kernel_launch(void* const* d_in, const int* in_sizes, int n_in,
                              void* d_out, int out_size, void* d_ws, size_t ws_size,
                              hipStream_t stream) {
  const float* x = (const float*)d_in[0];
  const int* ei = (const int*)d_in[1];
  const float* ea = (const float*)d_in[2];
  const float* W_xr = (const float*)d_in[3];
  const float* root_xr = (const float*)d_in[4];
  const float* b_xr = (const float*)d_in[5];
  const float* W_hr = (const float*)d_in[6];
  const float* root_hr = (const float*)d_in[7];
  const float* b_hr = (const float*)d_in[8];
  const float* W_xz = (const float*)d_in[9];
  const float* root_xz = (const float*)d_in[10];
  const float* b_xz = (const float*)d_in[11];
  const float* W_hz = (const float*)d_in[12];
  const float* root_hz = (const float*)d_in[13];
  const float* b_hz = (const float*)d_in[14];
  const float* W_xn = (const float*)d_in[15];
  const float* root_xn = (const float*)d_in[16];
  const float* b_xn = (const float*)d_in[17];

  char* w = (char*)d_ws;
  u16* xTb = (u16*)w;         w += (size_t)TSTEPS * NNODE * 32 * 2;   // 10.5 MB
  __half* xcr = (__half*)w;   w += (size_t)TSTEPS * NNODE * 64 * 2;   // 21 MB
  __half* xcz = (__half*)w;   w += (size_t)TSTEPS * NNODE * 64 * 2;   // 21 MB
  __half* xcn = (__half*)w;   w += (size_t)TSTEPS * NNODE * 64 * 2;   // 21 MB
  u16* hs = (u16*)w;          w += (size_t)TSTEPS * NNODE * 64 * 2;   // 21 MB
  float* h0 = (float*)w;      w += (size_t)NNODE * HOUT * 4;
  float* h1 = (float*)w;      w += (size_t)NNODE * HOUT * 4;
  u16* h0b = (u16*)w;         w += (size_t)NNODE * HOUT * 2;
  u16* h1b = (u16*)w;         w += (size_t)NNODE * HOUT * 2;
  float4* ebasis = (float4*)w; w += (size_t)(EDGES + 16) * 16;
  int* emeta = (int*)w;       w += (size_t)(EDGES + 16) * 4;
  u16* WhrT = (u16*)w;        w += (size_t)64 * KT_H * 2;
  u16* WhzT = (u16*)w;        w += (size_t)64 * KT_H * 2;
  u16* WxrT = (u16*)w;        w += (size_t)64 * KT_X * 2;
  u16* WxzT = (u16*)w;        w += (size_t)64 * KT_X * 2;
  u16* WxnT = (u16*)w;        w += (size_t)64 * KT_X * 2;
  int* degi = (int*)w;        w += (size_t)NNODE * 4;
  int* cursor = (int*)w;      w += (size_t)NNODE * 4;
  float* deg_inv = (float*)w; w += (size_t)NNODE * 4;
  int* rp = (int*)w;          w += (size_t)(NNODE + 4) * 4;

  hipMemsetAsync(degi, 0, (size_t)NNODE * 4, stream);
  hipMemsetAsync(cursor, 0, (size_t)NNODE * 4, stream);
  hipMemsetAsync(h0, 0, (size_t)NNODE * HOUT * 4, stream);
  hipMemsetAsync(h0b, 0, (size_t)NNODE * HOUT * 2, stream);

  xpose_kernel<<<(NNODE * 32 + 255) / 256, 256, 0, stream>>>(x, xTb);
  deg_kernel<<<(EDGES + 255) / 256, 256, 0, stream>>>(ei, degi);
  scan_kernel<<<1, 1024, 0, stream>>>(degi, rp, deg_inv);
  scatter_kernel<<<(EDGES + 255) / 256, 256, 0, stream>>>(ei, ea, rp, cursor, emeta,
                                                          ebasis);
  wprep_kernel<<<(64 * KT_H + 255) / 256, 256, 0, stream>>>(W_hr, root_hr, WhrT, 1600, KT_H);
  wprep_kernel<<<(64 * KT_H + 255) / 256, 256, 0, stream>>>(W_hz, root_hz, WhzT, 1600, KT_H);
  wprep_kernel<<<(64 * KT_X + 255) / 256, 256, 0, stream>>>(W_xr, root_xr, WxrT, 800, KT_X);
  wprep_kernel<<<(64 * KT_X + 255) / 256, 256, 0, stream>>>(W_xz, root_xz, WxzT, 800, KT_X);
  wprep_kernel<<<(64 * KT_X + 255) / 256, 256, 0, stream>>>(W_xn, root_xn, WxnT, 800, KT_X);

  XP xp;
  xp.xTb = xTb;
  xp.rp = rp;
  xp.emeta = emeta;
  xp.ebasis = ebasis;
  xp.deg_inv = deg_inv;
  xp.WxrT = WxrT; xp.WxzT = WxzT; xp.WxnT = WxnT;
  xp.b_xr = b_xr; xp.b_xz = b_xz; xp.b_xn = b_xn;
  xp.xcr = xcr; xp.xcz = xcz; xp.xcn = xcn;
  xc_kernel<<<dim3(NNODE / NBX, TSTEPS), 256, 0, stream>>>(xp);

  GP p;
  p.rp = rp;
  p.emeta = emeta;
  p.ebasis = ebasis;
  p.deg_inv = deg_inv;
  p.WhrT = WhrT; p.WhzT = WhzT;
  p.b_hr = b_hr; p.b_hz = b_hz;
  p.xcr = xcr; p.xcz = xcz; p.xcn = xcn;
  p.hs = hs;

  float* ha = h0; float* hb_ = h1;
  u16* hab = h0b; u16* hbb = h1b;
  for (int t = 0; t < TSTEPS; ++t) {
    p.h_cur = ha; p.h_curb = hab;
    p.h_next = hb_; p.h_nextb = hbb;
    gcgru_step<<<NNODE / NB, 256, 0, stream>>>(p, t);
    float* tf = ha; ha = hb_; hb_ = tf;
    u16* tb = hab; hab = hbb; hbb = tb;
  }

  float* out = (float*)d_out;
  float* out_last = out + (size_t)NNODE * HOUT * TSTEPS;
  finalize_kernel<<<(NNODE * 64 + 255) / 256, 256, 0, stream>>>(hs, out, out_last);
}